// Round 13
// baseline (132.688 us; speedup 1.0000x reference)
//
#include <hip/hip_runtime.h>
#include <math.h>

typedef unsigned short US;
typedef __attribute__((ext_vector_type(8))) __bf16 bf16x8;
typedef __attribute__((ext_vector_type(4))) float f32x4;
typedef __attribute__((ext_vector_type(4))) unsigned short us4;

#define MFMA16(a, b, c) __builtin_amdgcn_mfma_f32_16x16x32_bf16(a, b, c, 0, 0, 0)

__device__ __forceinline__ US f2bf(float f) {
  union { float f; unsigned u; } v; v.f = f;
  unsigned r = v.u + 0x7fffu + ((v.u >> 16) & 1u);
  return (US)(r >> 16);
}
__device__ __forceinline__ US f2bf_hw(float f) {  // compiler emits v_cvt_pk_bf16_f32
  __bf16 b = (__bf16)f;
  union { __bf16 b; US u; } v; v.b = b; return v.u;
}
__device__ __forceinline__ float bf2f(US u) {
  union { unsigned u; float f; } v; v.u = ((unsigned)u) << 16; return v.f;
}

__device__ __forceinline__ void gload16(const void* g, void* l) {
  __builtin_amdgcn_global_load_lds(
      (const __attribute__((address_space(1))) unsigned int*)g,
      (__attribute__((address_space(3))) unsigned int*)l, 16, 0, 0);
}

// ---------------- convert f32 -> bf16 staging ----------------
__global__ __launch_bounds__(256) void convert_k(
    const float* __restrict__ x, const float* __restrict__ Wq,
    const float* __restrict__ Wk, const float* __restrict__ Wv,
    const float* __restrict__ Wo,
    US* __restrict__ xb, US* __restrict__ wqkv, US* __restrict__ wob) {
  long i = (long)blockIdx.x * blockDim.x + threadIdx.x;
  long e4 = i * 4;
  if (e4 >= 8388608L) return;
  const float* src; US* dst;
  if (e4 < 4194304L) { src = x + e4; dst = xb + e4; }
  else if (e4 < 7340032L) {
    long off = e4 - 4194304L;
    dst = wqkv + off;
    src = (off < 1048576L) ? Wq + off
        : (off < 2097152L ? Wk + (off - 1048576L) : Wv + (off - 2097152L));
  } else {
    long off = e4 - 7340032L;
    src = Wo + off; dst = wob + off;
  }
  float4 v = *(const float4*)src;
  us4 o; o.x = f2bf(v.x); o.y = f2bf(v.y); o.z = f2bf(v.z); o.w = f2bf(v.w);
  *(us4*)dst = o;
}

// ---------------- 128x64 bf16 GEMM, BK=64 (QKV) -------------------------
// grid (32,48) = 1536 blocks = 6/CU (LDS 24KB): TLP hides the stage drain.
// 4 waves: wr=w>>1 (64-row half), wc=w&1 (32-col half); acc[4][2].
// QKV epilogue: bias, Q scale (incl log2e), Q/K [B,H,S,L], V^T [B,H,L,S].
__global__ __launch_bounds__(256) void gemm128q(
    const US* __restrict__ A, const US* __restrict__ BT,
    int K, int lda, int ldb,
    const float* __restrict__ b0, const float* __restrict__ b1,
    const float* __restrict__ b2,
    US* __restrict__ oQ, US* __restrict__ oK, US* __restrict__ oV) {
  __shared__ __align__(16) US As[2][128 * 32];
  __shared__ __align__(16) US Bs[2][64 * 32];
  const int tid = threadIdx.x, lane = tid & 63;
  const int w = tid >> 6, wr = w >> 1, wc = w & 1;
  const int m0 = blockIdx.x * 128, n0 = blockIdx.y * 64;
  f32x4 acc[4][2] = {};
  const int r0 = tid >> 2, c0 = (tid & 3) * 8;

  for (int kt = 0; kt < K; kt += 64) {
#pragma unroll
    for (int h = 0; h < 2; ++h) {
      gload16(A + (size_t)(m0 + r0) * lda + kt + h * 32 + c0, As[h] + tid * 8);
      gload16(A + (size_t)(m0 + r0 + 64) * lda + kt + h * 32 + c0,
              As[h] + (tid + 256) * 8);
      gload16(BT + (size_t)(n0 + r0) * ldb + kt + h * 32 + c0, Bs[h] + tid * 8);
    }
    __syncthreads();
#pragma unroll
    for (int h = 0; h < 2; ++h) {
      bf16x8 af[4], bfm[2];
#pragma unroll
      for (int i = 0; i < 4; ++i)
        af[i] = *(const bf16x8*)(As[h] + (wr * 64 + i * 16 + (lane & 15)) * 32 +
                                 (lane >> 4) * 8);
#pragma unroll
      for (int j = 0; j < 2; ++j)
        bfm[j] = *(const bf16x8*)(Bs[h] + (wc * 32 + j * 16 + (lane & 15)) * 32 +
                                  (lane >> 4) * 8);
#pragma unroll
      for (int i = 0; i < 4; ++i)
#pragma unroll
        for (int j = 0; j < 2; ++j)
          acc[i][j] = MFMA16(af[i], bfm[j], acc[i][j]);
    }
    __syncthreads();
  }

#pragma unroll
  for (int i = 0; i < 4; ++i) {
#pragma unroll
    for (int j = 0; j < 2; ++j) {
#pragma unroll
      for (int r = 0; r < 4; ++r) {
        int m = m0 + wr * 64 + i * 16 + (lane >> 4) * 4 + r;
        int n = n0 + wc * 32 + j * 16 + (lane & 15);
        float v = acc[i][j][r];
        int bb = m >> 11, s = m & 2047;
        int sec = n >> 10, idx = n & 1023;
        int h = idx >> 6, l = idx & 63;
        size_t bhsl = (((size_t)bb * 16 + h) * 2048 + s) * 64 + l;
        // 0.125 (1/sqrt(64)) * log2(e): scores land in log2 domain
        if (sec == 0)      oQ[bhsl] = f2bf((v + b0[idx]) * 0.18033688f);
        else if (sec == 1) oK[bhsl] = f2bf(v + b1[idx]);
        else oV[(((size_t)bb * 16 + h) * 64 + l) * 2048 + s] = f2bf(v + b2[idx]);
      }
    }
  }
}

// ---------------- 128x64 bf16 GEMM, BK=64 (out-proj) --------------------
__global__ __launch_bounds__(256) void gemm128o(
    const US* __restrict__ A, const US* __restrict__ BT,
    int K, int lda, int ldb, int N,
    const float* __restrict__ b0, float* __restrict__ oF) {
  __shared__ __align__(16) US As[2][128 * 32];
  __shared__ __align__(16) US Bs[2][64 * 32];
  const int tid = threadIdx.x, lane = tid & 63;
  const int w = tid >> 6, wr = w >> 1, wc = w & 1;
  const int m0 = blockIdx.x * 128, n0 = blockIdx.y * 64;
  f32x4 acc[4][2] = {};
  const int r0 = tid >> 2, c0 = (tid & 3) * 8;

  for (int kt = 0; kt < K; kt += 64) {
#pragma unroll
    for (int h = 0; h < 2; ++h) {
      gload16(A + (size_t)(m0 + r0) * lda + kt + h * 32 + c0, As[h] + tid * 8);
      gload16(A + (size_t)(m0 + r0 + 64) * lda + kt + h * 32 + c0,
              As[h] + (tid + 256) * 8);
      gload16(BT + (size_t)(n0 + r0) * ldb + kt + h * 32 + c0, Bs[h] + tid * 8);
    }
    __syncthreads();
#pragma unroll
    for (int h = 0; h < 2; ++h) {
      bf16x8 af[4], bfm[2];
#pragma unroll
      for (int i = 0; i < 4; ++i)
        af[i] = *(const bf16x8*)(As[h] + (wr * 64 + i * 16 + (lane & 15)) * 32 +
                                 (lane >> 4) * 8);
#pragma unroll
      for (int j = 0; j < 2; ++j)
        bfm[j] = *(const bf16x8*)(Bs[h] + (wc * 32 + j * 16 + (lane & 15)) * 32 +
                                  (lane >> 4) * 8);
#pragma unroll
      for (int i = 0; i < 4; ++i)
#pragma unroll
        for (int j = 0; j < 2; ++j)
          acc[i][j] = MFMA16(af[i], bfm[j], acc[i][j]);
    }
    __syncthreads();
  }

#pragma unroll
  for (int i = 0; i < 4; ++i)
#pragma unroll
    for (int j = 0; j < 2; ++j)
#pragma unroll
      for (int r = 0; r < 4; ++r) {
        int m = m0 + wr * 64 + i * 16 + (lane >> 4) * 4 + r;
        int n = n0 + wc * 32 + j * 16 + (lane & 15);
        oF[(size_t)m * N + n] = acc[i][j][r] + b0[n];
      }
}

// ---------------- causal flash attention, split-KV x2 ----------------
// grid 2048: slot-major: slot=bx>>6 (qt=31-slot), bh=(bx&63)>>1, half=bx&1.
// Scores in log2 domain -> exp2f softmax; T13 defer-max; HW cvt for P-pack.
__global__ __launch_bounds__(256) void attn_k(
    const US* __restrict__ Qb, const US* __restrict__ Kb,
    const US* __restrict__ Vtb, US* __restrict__ opart,
    float2* __restrict__ mlpart) {
  __shared__ __align__(16) US Ks[64 * 64];
  __shared__ __align__(16) US Vs[64 * 64];
  __shared__ __align__(16) US Ps[4][16 * 72];
  const int tid = threadIdx.x, lane = tid & 63, w = tid >> 6;
  const int slot = blockIdx.x >> 6;
  const int qt = 31 - slot;
  const int bh = (blockIdx.x & 63) >> 1;
  const int half = blockIdx.x & 1;
  const int h0 = (qt + 2) >> 1;
  const int kstart = half ? h0 : 0;
  const int kend = half ? (qt + 1) : h0;
  const size_t pslot = (size_t)(bh * 32 + qt) * 2 + half;

  if (kstart >= kend) {  // empty half (qt==0, half==1): zero O, neutral ml
    US* op = opart + pslot * 4096;
    us4 z; z.x = 0; z.y = 0; z.z = 0; z.w = 0;
#pragma unroll
    for (int j = 0; j < 4; ++j) *(us4*)(op + tid * 16 + j * 4) = z;
    if ((lane >> 4) == 0)
      mlpart[pslot * 64 + w * 16 + lane] = make_float2(-INFINITY, 0.f);
    return;
  }

  const US* Qp = Qb + ((size_t)bh * 2048 + qt * 64) * 64;
  const char* Kbase = (const char*)(Kb + (size_t)bh * 2048 * 64);
  const char* Vbase = (const char*)(Vtb + (size_t)bh * 64 * 2048);

  const int row0 = tid >> 3, col16 = (tid & 7) * 16;
  const int row1 = row0 + 32;
  const int soff0 = (row0 * 128 + col16) ^ ((row0 & 7) << 4);
  const int soff1 = soff0 + 32 * 128;

  bf16x8 aq[2];
  {
    int qrow = w * 16 + (lane & 15);
#pragma unroll
    for (int kk = 0; kk < 2; ++kk)
      aq[kk] = *(const bf16x8*)(Qp + qrow * 64 + kk * 32 + (lane >> 4) * 8);
  }
  f32x4 o[4] = {};
  float m = -INFINITY, l = 0.f;  // per-lane: q = lane&15 of this wave's tile

  int4 rk0, rk1, rv0, rv1;
#define LOADT(KT)                                                              \
  do {                                                                         \
    rk0 = *(const int4*)(Kbase + ((size_t)((KT)*64 + row0)) * 128 + col16);    \
    rk1 = *(const int4*)(Kbase + ((size_t)((KT)*64 + row1)) * 128 + col16);    \
    rv0 = *(const int4*)(Vbase + (size_t)row0 * 4096 + (KT)*128 + col16);      \
    rv1 = *(const int4*)(Vbase + (size_t)row1 * 4096 + (KT)*128 + col16);      \
  } while (0)
#define WRITET()                                                               \
  do {                                                                         \
    *(int4*)((char*)Ks + soff0) = rk0;                                         \
    *(int4*)((char*)Ks + soff1) = rk1;                                         \
    *(int4*)((char*)Vs + soff0) = rv0;                                         \
    *(int4*)((char*)Vs + soff1) = rv1;                                         \
  } while (0)

  LOADT(kstart);
  WRITET();
  __syncthreads();

  for (int kt = kstart; kt < kend; ++kt) {
    if (kt + 1 < kend) LOADT(kt + 1);  // in flight during compute (T14)

    // ---- QK^T, swapped: D[kv][q], q = lane&15, kv = nt*16+(lane>>4)*4+r ----
    f32x4 sc[4];
    __builtin_amdgcn_s_setprio(1);
#pragma unroll
    for (int nt = 0; nt < 4; ++nt) {
      f32x4 s = {0.f, 0.f, 0.f, 0.f};
#pragma unroll
      for (int kk = 0; kk < 2; ++kk) {
        int rr = nt * 16 + (lane & 15);
        int off = rr * 128 + kk * 64 + (lane >> 4) * 16;
        off ^= (rr & 7) << 4;
        bf16x8 bkf = *(const bf16x8*)((const char*)Ks + off);
        s = MFMA16(bkf, aq[kk], s);  // swapped operands
      }
      sc[nt] = s;
    }
    __builtin_amdgcn_s_setprio(0);

    if (kt == qt) {  // diagonal tile: causal mask (kv > q within tile)
      int q_in = w * 16 + (lane & 15);
#pragma unroll
      for (int nt = 0; nt < 4; ++nt)
#pragma unroll
        for (int r = 0; r < 4; ++r) {
          int kv_in = nt * 16 + (lane >> 4) * 4 + r;
          if (kv_in > q_in) sc[nt][r] = -INFINITY;
        }
    }

    // ---- in-lane online softmax (log2 domain), T13 defer-max ----
    {
      float m01 = fmaxf(fmaxf(sc[0][0], sc[0][1]), fmaxf(sc[0][2], sc[0][3]));
      float m23 = fmaxf(fmaxf(sc[1][0], sc[1][1]), fmaxf(sc[1][2], sc[1][3]));
      float m45 = fmaxf(fmaxf(sc[2][0], sc[2][1]), fmaxf(sc[2][2], sc[2][3]));
      float m67 = fmaxf(fmaxf(sc[3][0], sc[3][1]), fmaxf(sc[3][2], sc[3][3]));
      float mx = fmaxf(fmaxf(m01, m23), fmaxf(m45, m67));
      mx = fmaxf(mx, __shfl_xor(mx, 16));
      mx = fmaxf(mx, __shfl_xor(mx, 32));
      if (__any(mx - m > 8.f)) {  // rescale only on material max growth
        float mnew = fmaxf(m, mx);
        float scale = exp2f(m - mnew);
        m = mnew;
        l *= scale;
#pragma unroll
        for (int r = 0; r < 4; ++r) {
          float sr = __shfl(scale, ((lane >> 4) << 2) + r, 64);
          o[0][r] *= sr; o[1][r] *= sr; o[2][r] *= sr; o[3][r] *= sr;
        }
      }
      float s0 = 0.f, s1 = 0.f, s2 = 0.f, s3 = 0.f;
#pragma unroll
      for (int nt = 0; nt < 4; ++nt) {
        float p0 = exp2f(sc[nt][0] - m);
        float p1 = exp2f(sc[nt][1] - m);
        float p2 = exp2f(sc[nt][2] - m);
        float p3 = exp2f(sc[nt][3] - m);
        sc[nt][0] = p0; sc[nt][1] = p1; sc[nt][2] = p2; sc[nt][3] = p3;
        s0 += p0; s1 += p1; s2 += p2; s3 += p3;
      }
      float ssum = (s0 + s1) + (s2 + s3);
      ssum += __shfl_xor(ssum, 16);
      ssum += __shfl_xor(ssum, 32);
      l += ssum;
    }

    // ---- P -> LDS: Ps[q][kv], HW bf16 cvt (compiler emits cvt_pk) ----
    US* pp = &Ps[w][0];
    const int pbase = (lane & 15) * 72 + (lane >> 4) * 4;
#pragma unroll
    for (int nt = 0; nt < 4; ++nt) {
      us4 w4;
      w4.x = f2bf_hw(sc[nt][0]); w4.y = f2bf_hw(sc[nt][1]);
      w4.z = f2bf_hw(sc[nt][2]); w4.w = f2bf_hw(sc[nt][3]);
      *(us4*)(pp + pbase + nt * 16) = w4;
    }

    // ---- PV ----
    __builtin_amdgcn_s_setprio(1);
#pragma unroll
    for (int kk = 0; kk < 2; ++kk) {
      bf16x8 pa = *(const bf16x8*)(pp + (lane & 15) * 72 + kk * 32 + (lane >> 4) * 8);
#pragma unroll
      for (int nt = 0; nt < 4; ++nt) {
        int rr = nt * 16 + (lane & 15);
        int off = rr * 128 + kk * 64 + (lane >> 4) * 16;
        off ^= (rr & 7) << 4;
        bf16x8 bvf = *(const bf16x8*)((const char*)Vs + off);
        o[nt] = MFMA16(pa, bvf, o[nt]);
      }
    }
    __builtin_amdgcn_s_setprio(0);

    __syncthreads();
    if (kt + 1 < kend) {
      WRITET();
      __syncthreads();
    }
  }
#undef LOADT
#undef WRITET

  // epilogue: unnormalized partial O (bf16) + per-row m,l
  US* op = opart + pslot * 4096;
#pragma unroll
  for (int r = 0; r < 4; ++r) {
    int row = w * 16 + (lane >> 4) * 4 + r;
#pragma unroll
    for (int nt = 0; nt < 4; ++nt) {
      int d = nt * 16 + (lane & 15);
      op[row * 64 + d] = f2bf_hw(o[nt][r]);
    }
  }
  if ((lane >> 4) == 0)
    mlpart[pslot * 64 + w * 16 + lane] = make_float2(m, l);
}

// ---------------- merge split-KV partials -> zb (log2-domain m) --------
__global__ __launch_bounds__(256) void merge_k(
    const US* __restrict__ opart, const float2* __restrict__ mlpart,
    US* __restrict__ zb) {
  const int t = blockIdx.x;
  const int bh = t >> 5, qt = t & 31;
  const int b = bh >> 4, h = bh & 15;
  const int row = threadIdx.x >> 2;
  const int dg = (threadIdx.x & 3) * 16;
  const US* o1 = opart + ((size_t)t * 2 + 0) * 4096 + row * 64 + dg;
  const US* o2 = opart + ((size_t)t * 2 + 1) * 4096 + row * 64 + dg;
  float2 ml1 = mlpart[(t * 2 + 0) * 64 + row];
  float2 ml2 = mlpart[(t * 2 + 1) * 64 + row];
  float mm = fmaxf(ml1.x, ml2.x);
  float w1 = exp2f(ml1.x - mm), w2 = exp2f(ml2.x - mm);
  float li = 1.0f / (ml1.y * w1 + ml2.y * w2);
  w1 *= li; w2 *= li;
  int s = qt * 64 + row;
  US* dst = zb + ((size_t)b * 2048 + s) * 1024 + h * 64 + dg;
#pragma unroll
  for (int j = 0; j < 4; ++j) {
    us4 a = *(const us4*)(o1 + j * 4);
    us4 c = *(const us4*)(o2 + j * 4);
    us4 r;
    r.x = f2bf(bf2f(a.x) * w1 + bf2f(c.x) * w2);
    r.y = f2bf(bf2f(a.y) * w1 + bf2f(c.y) * w2);
    r.z = f2bf(bf2f(a.z) * w1 + bf2f(c.z) * w2);
    r.w = f2bf(bf2f(a.w) * w1 + bf2f(c.w) * w2);
    *(us4*)(dst + j * 4) = r;
  }
}

extern "C" void kernel_launch(void* const* d_in, const int* in_sizes, int n_in,
                              void* d_out, int out_size, void* d_ws, size_t ws_size,
                              hipStream_t stream) {
  (void)in_sizes; (void)n_in; (void)out_size; (void)ws_size;
  const float* x  = (const float*)d_in[0];
  const float* Wq = (const float*)d_in[2];
  const float* bq = (const float*)d_in[3];
  const float* Wk = (const float*)d_in[4];
  const float* bk = (const float*)d_in[5];
  const float* Wv = (const float*)d_in[6];
  const float* bv = (const float*)d_in[7];
  const float* Wo = (const float*)d_in[8];
  const float* bo = (const float*)d_in[9];
  char* ws = (char*)d_ws;
  US* xb     = (US*)(ws);
  float2* ml = (float2*)(ws);
  US* zb     = (US*)(ws + 1048576);
  US* wqkv   = (US*)(ws + 8388608);
  US* wob    = (US*)(ws + 14680064);
  US* Qb     = (US*)(ws + 16777216);
  US* Kb     = (US*)(ws + 25165824);
  US* Vtb    = (US*)(ws + 33554432);
  US* opart  = (US*)d_out;
  float* out = (float*)d_out;

  convert_k<<<dim3(8192), dim3(256), 0, stream>>>(x, Wq, Wk, Wv, Wo, xb, wqkv, wob);
  gemm128q<<<dim3(32, 48), dim3(256), 0, stream>>>(
      xb, wqkv, 1024, 1024, 1024, bq, bk, bv, Qb, Kb, Vtb);
  attn_k<<<dim3(2048), dim3(256), 0, stream>>>(Qb, Kb, Vtb, opart, ml);
  merge_k<<<dim3(1024), dim3(256), 0, stream>>>(opart, ml, zb);
  gemm128o<<<dim3(32, 16), dim3(256), 0, stream>>>(
      zb, wob, 1024, 1024, 1024, 1024, bo, out);
}

// Round 14
// 126.459 us; speedup vs baseline: 1.0493x; 1.0493x over previous
//
#include <hip/hip_runtime.h>
#include <math.h>

typedef unsigned short US;
typedef __attribute__((ext_vector_type(8))) __bf16 bf16x8;
typedef __attribute__((ext_vector_type(4))) float f32x4;
typedef __attribute__((ext_vector_type(4))) unsigned short us4;

#define MFMA16(a, b, c) __builtin_amdgcn_mfma_f32_16x16x32_bf16(a, b, c, 0, 0, 0)

__device__ __forceinline__ US f2bf(float f) {
  union { float f; unsigned u; } v; v.f = f;
  unsigned r = v.u + 0x7fffu + ((v.u >> 16) & 1u);
  return (US)(r >> 16);
}
__device__ __forceinline__ US f2bf_hw(float f) {  // compiler emits v_cvt_pk_bf16_f32
  __bf16 b = (__bf16)f;
  union { __bf16 b; US u; } v; v.b = b; return v.u;
}
__device__ __forceinline__ float bf2f(US u) {
  union { unsigned u; float f; } v; v.u = ((unsigned)u) << 16; return v.f;
}

__device__ __forceinline__ void gload16(const void* g, void* l) {
  __builtin_amdgcn_global_load_lds(
      (const __attribute__((address_space(1))) unsigned int*)g,
      (__attribute__((address_space(3))) unsigned int*)l, 16, 0, 0);
}

// ---------------- convert f32 -> bf16 staging (grid-stride, G11) --------
__global__ __launch_bounds__(256) void convert_k(
    const float* __restrict__ x, const float* __restrict__ Wq,
    const float* __restrict__ Wk, const float* __restrict__ Wv,
    const float* __restrict__ Wo,
    US* __restrict__ xb, US* __restrict__ wqkv, US* __restrict__ wob) {
  const long stride = (long)gridDim.x * blockDim.x * 4;
  for (long e4 = ((long)blockIdx.x * blockDim.x + threadIdx.x) * 4;
       e4 < 8388608L; e4 += stride) {
    const float* src; US* dst;
    if (e4 < 4194304L) { src = x + e4; dst = xb + e4; }
    else if (e4 < 7340032L) {
      long off = e4 - 4194304L;
      dst = wqkv + off;
      src = (off < 1048576L) ? Wq + off
          : (off < 2097152L ? Wk + (off - 1048576L) : Wv + (off - 2097152L));
    } else {
      long off = e4 - 7340032L;
      src = Wo + off; dst = wob + off;
    }
    float4 v = *(const float4*)src;
    us4 o; o.x = f2bf(v.x); o.y = f2bf(v.y); o.z = f2bf(v.z); o.w = f2bf(v.w);
    *(us4*)dst = o;
  }
}

// ---------------- 128x128 bf16 GEMM, BK=64 (QKV, round-12 proven) -------
// QKV epilogue: bias, Q scale (incl log2e), Q/K [B,H,S,L], V^T [B,H,L,S].
__global__ __launch_bounds__(256) void gemm128q(
    const US* __restrict__ A, const US* __restrict__ BT,
    int K, int lda, int ldb,
    const float* __restrict__ b0, const float* __restrict__ b1,
    const float* __restrict__ b2,
    US* __restrict__ oQ, US* __restrict__ oK, US* __restrict__ oV) {
  __shared__ __align__(16) US As[2][128 * 32];
  __shared__ __align__(16) US Bs[2][128 * 32];
  const int tid = threadIdx.x, lane = tid & 63;
  const int w = tid >> 6, wr = w >> 1, wc = w & 1;
  const int m0 = blockIdx.x * 128, n0 = blockIdx.y * 128;
  f32x4 acc[4][4] = {};
  const int r0 = tid >> 2, c0 = (tid & 3) * 8;

  for (int kt = 0; kt < K; kt += 64) {
#pragma unroll
    for (int h = 0; h < 2; ++h) {
      gload16(A + (size_t)(m0 + r0) * lda + kt + h * 32 + c0, As[h] + tid * 8);
      gload16(A + (size_t)(m0 + r0 + 64) * lda + kt + h * 32 + c0,
              As[h] + (tid + 256) * 8);
      gload16(BT + (size_t)(n0 + r0) * ldb + kt + h * 32 + c0, Bs[h] + tid * 8);
      gload16(BT + (size_t)(n0 + r0 + 64) * ldb + kt + h * 32 + c0,
              Bs[h] + (tid + 256) * 8);
    }
    __syncthreads();
#pragma unroll
    for (int h = 0; h < 2; ++h) {
      bf16x8 af[4], bfm[4];
#pragma unroll
      for (int i = 0; i < 4; ++i)
        af[i] = *(const bf16x8*)(As[h] + (wr * 64 + i * 16 + (lane & 15)) * 32 +
                                 (lane >> 4) * 8);
#pragma unroll
      for (int j = 0; j < 4; ++j)
        bfm[j] = *(const bf16x8*)(Bs[h] + (wc * 64 + j * 16 + (lane & 15)) * 32 +
                                  (lane >> 4) * 8);
#pragma unroll
      for (int i = 0; i < 4; ++i)
#pragma unroll
        for (int j = 0; j < 4; ++j)
          acc[i][j] = MFMA16(af[i], bfm[j], acc[i][j]);
    }
    __syncthreads();
  }

#pragma unroll
  for (int i = 0; i < 4; ++i) {
#pragma unroll
    for (int j = 0; j < 4; ++j) {
#pragma unroll
      for (int r = 0; r < 4; ++r) {
        int m = m0 + wr * 64 + i * 16 + (lane >> 4) * 4 + r;
        int n = n0 + wc * 64 + j * 16 + (lane & 15);
        float v = acc[i][j][r];
        int bb = m >> 11, s = m & 2047;
        int sec = n >> 10, idx = n & 1023;
        int h = idx >> 6, l = idx & 63;
        size_t bhsl = (((size_t)bb * 16 + h) * 2048 + s) * 64 + l;
        // 0.125 (1/sqrt(64)) * log2(e): scores land in log2 domain
        if (sec == 0)      oQ[bhsl] = f2bf((v + b0[idx]) * 0.18033688f);
        else if (sec == 1) oK[bhsl] = f2bf(v + b1[idx]);
        else oV[(((size_t)bb * 16 + h) * 64 + l) * 2048 + s] = f2bf(v + b2[idx]);
      }
    }
  }
}

// ---------------- 128x64 bf16 GEMM, BK=64 (out-proj) --------------------
__global__ __launch_bounds__(256) void gemm128o(
    const US* __restrict__ A, const US* __restrict__ BT,
    int K, int lda, int ldb, int N,
    const float* __restrict__ b0, float* __restrict__ oF) {
  __shared__ __align__(16) US As[2][128 * 32];
  __shared__ __align__(16) US Bs[2][64 * 32];
  const int tid = threadIdx.x, lane = tid & 63;
  const int w = tid >> 6, wr = w >> 1, wc = w & 1;
  const int m0 = blockIdx.x * 128, n0 = blockIdx.y * 64;
  f32x4 acc[4][2] = {};
  const int r0 = tid >> 2, c0 = (tid & 3) * 8;

  for (int kt = 0; kt < K; kt += 64) {
#pragma unroll
    for (int h = 0; h < 2; ++h) {
      gload16(A + (size_t)(m0 + r0) * lda + kt + h * 32 + c0, As[h] + tid * 8);
      gload16(A + (size_t)(m0 + r0 + 64) * lda + kt + h * 32 + c0,
              As[h] + (tid + 256) * 8);
      gload16(BT + (size_t)(n0 + r0) * ldb + kt + h * 32 + c0, Bs[h] + tid * 8);
    }
    __syncthreads();
#pragma unroll
    for (int h = 0; h < 2; ++h) {
      bf16x8 af[4], bfm[2];
#pragma unroll
      for (int i = 0; i < 4; ++i)
        af[i] = *(const bf16x8*)(As[h] + (wr * 64 + i * 16 + (lane & 15)) * 32 +
                                 (lane >> 4) * 8);
#pragma unroll
      for (int j = 0; j < 2; ++j)
        bfm[j] = *(const bf16x8*)(Bs[h] + (wc * 32 + j * 16 + (lane & 15)) * 32 +
                                  (lane >> 4) * 8);
#pragma unroll
      for (int i = 0; i < 4; ++i)
#pragma unroll
        for (int j = 0; j < 2; ++j)
          acc[i][j] = MFMA16(af[i], bfm[j], acc[i][j]);
    }
    __syncthreads();
  }

#pragma unroll
  for (int i = 0; i < 4; ++i)
#pragma unroll
    for (int j = 0; j < 2; ++j)
#pragma unroll
      for (int r = 0; r < 4; ++r) {
        int m = m0 + wr * 64 + i * 16 + (lane >> 4) * 4 + r;
        int n = n0 + wc * 32 + j * 16 + (lane & 15);
        oF[(size_t)m * N + n] = acc[i][j][r] + b0[n];
      }
}

// ---------------- causal flash attention, split-KV x2 ----------------
// grid 2048: slot-major: slot=bx>>6 (qt=31-slot), bh=(bx&63)>>1, half=bx&1.
// Scores in log2 domain -> exp2f softmax; T13 defer-max; HW cvt for P-pack.
__global__ __launch_bounds__(256) void attn_k(
    const US* __restrict__ Qb, const US* __restrict__ Kb,
    const US* __restrict__ Vtb, US* __restrict__ opart,
    float2* __restrict__ mlpart) {
  __shared__ __align__(16) US Ks[64 * 64];
  __shared__ __align__(16) US Vs[64 * 64];
  __shared__ __align__(16) US Ps[4][16 * 72];
  const int tid = threadIdx.x, lane = tid & 63, w = tid >> 6;
  const int slot = blockIdx.x >> 6;
  const int qt = 31 - slot;
  const int bh = (blockIdx.x & 63) >> 1;
  const int half = blockIdx.x & 1;
  const int h0 = (qt + 2) >> 1;
  const int kstart = half ? h0 : 0;
  const int kend = half ? (qt + 1) : h0;
  const size_t pslot = (size_t)(bh * 32 + qt) * 2 + half;

  if (kstart >= kend) {  // empty half (qt==0, half==1): zero O, neutral ml
    US* op = opart + pslot * 4096;
    us4 z; z.x = 0; z.y = 0; z.z = 0; z.w = 0;
#pragma unroll
    for (int j = 0; j < 4; ++j) *(us4*)(op + tid * 16 + j * 4) = z;
    if ((lane >> 4) == 0)
      mlpart[pslot * 64 + w * 16 + lane] = make_float2(-INFINITY, 0.f);
    return;
  }

  const US* Qp = Qb + ((size_t)bh * 2048 + qt * 64) * 64;
  const char* Kbase = (const char*)(Kb + (size_t)bh * 2048 * 64);
  const char* Vbase = (const char*)(Vtb + (size_t)bh * 64 * 2048);

  const int row0 = tid >> 3, col16 = (tid & 7) * 16;
  const int row1 = row0 + 32;
  const int soff0 = (row0 * 128 + col16) ^ ((row0 & 7) << 4);
  const int soff1 = soff0 + 32 * 128;

  bf16x8 aq[2];
  {
    int qrow = w * 16 + (lane & 15);
#pragma unroll
    for (int kk = 0; kk < 2; ++kk)
      aq[kk] = *(const bf16x8*)(Qp + qrow * 64 + kk * 32 + (lane >> 4) * 8);
  }
  f32x4 o[4] = {};
  float m = -INFINITY, l = 0.f;  // per-lane: q = lane&15 of this wave's tile

  int4 rk0, rk1, rv0, rv1;
#define LOADT(KT)                                                              \
  do {                                                                         \
    rk0 = *(const int4*)(Kbase + ((size_t)((KT)*64 + row0)) * 128 + col16);    \
    rk1 = *(const int4*)(Kbase + ((size_t)((KT)*64 + row1)) * 128 + col16);    \
    rv0 = *(const int4*)(Vbase + (size_t)row0 * 4096 + (KT)*128 + col16);      \
    rv1 = *(const int4*)(Vbase + (size_t)row1 * 4096 + (KT)*128 + col16);      \
  } while (0)
#define WRITET()                                                               \
  do {                                                                         \
    *(int4*)((char*)Ks + soff0) = rk0;                                         \
    *(int4*)((char*)Ks + soff1) = rk1;                                         \
    *(int4*)((char*)Vs + soff0) = rv0;                                         \
    *(int4*)((char*)Vs + soff1) = rv1;                                         \
  } while (0)

  LOADT(kstart);
  WRITET();
  __syncthreads();

  for (int kt = kstart; kt < kend; ++kt) {
    if (kt + 1 < kend) LOADT(kt + 1);  // in flight during compute (T14)

    // ---- QK^T, swapped: D[kv][q], q = lane&15, kv = nt*16+(lane>>4)*4+r ----
    f32x4 sc[4];
    __builtin_amdgcn_s_setprio(1);
#pragma unroll
    for (int nt = 0; nt < 4; ++nt) {
      f32x4 s = {0.f, 0.f, 0.f, 0.f};
#pragma unroll
      for (int kk = 0; kk < 2; ++kk) {
        int rr = nt * 16 + (lane & 15);
        int off = rr * 128 + kk * 64 + (lane >> 4) * 16;
        off ^= (rr & 7) << 4;
        bf16x8 bkf = *(const bf16x8*)((const char*)Ks + off);
        s = MFMA16(bkf, aq[kk], s);  // swapped operands
      }
      sc[nt] = s;
    }
    __builtin_amdgcn_s_setprio(0);

    if (kt == qt) {  // diagonal tile: causal mask (kv > q within tile)
      int q_in = w * 16 + (lane & 15);
#pragma unroll
      for (int nt = 0; nt < 4; ++nt)
#pragma unroll
        for (int r = 0; r < 4; ++r) {
          int kv_in = nt * 16 + (lane >> 4) * 4 + r;
          if (kv_in > q_in) sc[nt][r] = -INFINITY;
        }
    }

    // ---- in-lane online softmax (log2 domain), T13 defer-max ----
    {
      float m01 = fmaxf(fmaxf(sc[0][0], sc[0][1]), fmaxf(sc[0][2], sc[0][3]));
      float m23 = fmaxf(fmaxf(sc[1][0], sc[1][1]), fmaxf(sc[1][2], sc[1][3]));
      float m45 = fmaxf(fmaxf(sc[2][0], sc[2][1]), fmaxf(sc[2][2], sc[2][3]));
      float m67 = fmaxf(fmaxf(sc[3][0], sc[3][1]), fmaxf(sc[3][2], sc[3][3]));
      float mx = fmaxf(fmaxf(m01, m23), fmaxf(m45, m67));
      mx = fmaxf(mx, __shfl_xor(mx, 16));
      mx = fmaxf(mx, __shfl_xor(mx, 32));
      if (__any(mx - m > 8.f)) {  // rescale only on material max growth
        float mnew = fmaxf(m, mx);
        float scale = exp2f(m - mnew);
        m = mnew;
        l *= scale;
#pragma unroll
        for (int r = 0; r < 4; ++r) {
          float sr = __shfl(scale, ((lane >> 4) << 2) + r, 64);
          o[0][r] *= sr; o[1][r] *= sr; o[2][r] *= sr; o[3][r] *= sr;
        }
      }
      float s0 = 0.f, s1 = 0.f, s2 = 0.f, s3 = 0.f;
#pragma unroll
      for (int nt = 0; nt < 4; ++nt) {
        float p0 = exp2f(sc[nt][0] - m);
        float p1 = exp2f(sc[nt][1] - m);
        float p2 = exp2f(sc[nt][2] - m);
        float p3 = exp2f(sc[nt][3] - m);
        sc[nt][0] = p0; sc[nt][1] = p1; sc[nt][2] = p2; sc[nt][3] = p3;
        s0 += p0; s1 += p1; s2 += p2; s3 += p3;
      }
      float ssum = (s0 + s1) + (s2 + s3);
      ssum += __shfl_xor(ssum, 16);
      ssum += __shfl_xor(ssum, 32);
      l += ssum;
    }

    // ---- P -> LDS: Ps[q][kv], HW bf16 cvt (compiler emits cvt_pk) ----
    US* pp = &Ps[w][0];
    const int pbase = (lane & 15) * 72 + (lane >> 4) * 4;
#pragma unroll
    for (int nt = 0; nt < 4; ++nt) {
      us4 w4;
      w4.x = f2bf_hw(sc[nt][0]); w4.y = f2bf_hw(sc[nt][1]);
      w4.z = f2bf_hw(sc[nt][2]); w4.w = f2bf_hw(sc[nt][3]);
      *(us4*)(pp + pbase + nt * 16) = w4;
    }

    // ---- PV ----
    __builtin_amdgcn_s_setprio(1);
#pragma unroll
    for (int kk = 0; kk < 2; ++kk) {
      bf16x8 pa = *(const bf16x8*)(pp + (lane & 15) * 72 + kk * 32 + (lane >> 4) * 8);
#pragma unroll
      for (int nt = 0; nt < 4; ++nt) {
        int rr = nt * 16 + (lane & 15);
        int off = rr * 128 + kk * 64 + (lane >> 4) * 16;
        off ^= (rr & 7) << 4;
        bf16x8 bvf = *(const bf16x8*)((const char*)Vs + off);
        o[nt] = MFMA16(pa, bvf, o[nt]);
      }
    }
    __builtin_amdgcn_s_setprio(0);

    __syncthreads();
    if (kt + 1 < kend) {
      WRITET();
      __syncthreads();
    }
  }
#undef LOADT
#undef WRITET

  // epilogue: unnormalized partial O (bf16) + per-row m,l
  US* op = opart + pslot * 4096;
#pragma unroll
  for (int r = 0; r < 4; ++r) {
    int row = w * 16 + (lane >> 4) * 4 + r;
#pragma unroll
    for (int nt = 0; nt < 4; ++nt) {
      int d = nt * 16 + (lane & 15);
      op[row * 64 + d] = f2bf_hw(o[nt][r]);
    }
  }
  if ((lane >> 4) == 0)
    mlpart[pslot * 64 + w * 16 + lane] = make_float2(m, l);
}

// ---------------- merge split-KV partials -> zb (log2-domain m) --------
__global__ __launch_bounds__(256) void merge_k(
    const US* __restrict__ opart, const float2* __restrict__ mlpart,
    US* __restrict__ zb) {
  const int t = blockIdx.x;
  const int bh = t >> 5, qt = t & 31;
  const int b = bh >> 4, h = bh & 15;
  const int row = threadIdx.x >> 2;
  const int dg = (threadIdx.x & 3) * 16;
  const US* o1 = opart + ((size_t)t * 2 + 0) * 4096 + row * 64 + dg;
  const US* o2 = opart + ((size_t)t * 2 + 1) * 4096 + row * 64 + dg;
  float2 ml1 = mlpart[(t * 2 + 0) * 64 + row];
  float2 ml2 = mlpart[(t * 2 + 1) * 64 + row];
  float mm = fmaxf(ml1.x, ml2.x);
  float w1 = exp2f(ml1.x - mm), w2 = exp2f(ml2.x - mm);
  float li = 1.0f / (ml1.y * w1 + ml2.y * w2);
  w1 *= li; w2 *= li;
  int s = qt * 64 + row;
  US* dst = zb + ((size_t)b * 2048 + s) * 1024 + h * 64 + dg;
#pragma unroll
  for (int j = 0; j < 4; ++j) {
    us4 a = *(const us4*)(o1 + j * 4);
    us4 c = *(const us4*)(o2 + j * 4);
    us4 r;
    r.x = f2bf(bf2f(a.x) * w1 + bf2f(c.x) * w2);
    r.y = f2bf(bf2f(a.y) * w1 + bf2f(c.y) * w2);
    r.z = f2bf(bf2f(a.z) * w1 + bf2f(c.z) * w2);
    r.w = f2bf(bf2f(a.w) * w1 + bf2f(c.w) * w2);
    *(us4*)(dst + j * 4) = r;
  }
}

extern "C" void kernel_launch(void* const* d_in, const int* in_sizes, int n_in,
                              void* d_out, int out_size, void* d_ws, size_t ws_size,
                              hipStream_t stream) {
  (void)in_sizes; (void)n_in; (void)out_size; (void)ws_size;
  const float* x  = (const float*)d_in[0];
  const float* Wq = (const float*)d_in[2];
  const float* bq = (const float*)d_in[3];
  const float* Wk = (const float*)d_in[4];
  const float* bk = (const float*)d_in[5];
  const float* Wv = (const float*)d_in[6];
  const float* bv = (const float*)d_in[7];
  const float* Wo = (const float*)d_in[8];
  const float* bo = (const float*)d_in[9];
  char* ws = (char*)d_ws;
  US* xb     = (US*)(ws);
  float2* ml = (float2*)(ws);
  US* zb     = (US*)(ws + 1048576);
  US* wqkv   = (US*)(ws + 8388608);
  US* wob    = (US*)(ws + 14680064);
  US* Qb     = (US*)(ws + 16777216);
  US* Kb     = (US*)(ws + 25165824);
  US* Vtb    = (US*)(ws + 33554432);
  US* opart  = (US*)d_out;
  float* out = (float*)d_out;

  convert_k<<<dim3(2048), dim3(256), 0, stream>>>(x, Wq, Wk, Wv, Wo, xb, wqkv, wob);
  gemm128q<<<dim3(32, 24), dim3(256), 0, stream>>>(
      xb, wqkv, 1024, 1024, 1024, bq, bk, bv, Qb, Kb, Vtb);
  attn_k<<<dim3(2048), dim3(256), 0, stream>>>(Qb, Kb, Vtb, opart, ml);
  merge_k<<<dim3(1024), dim3(256), 0, stream>>>(opart, ml, zb);
  gemm128o<<<dim3(32, 16), dim3(256), 0, stream>>>(
      zb, wob, 1024, 1024, 1024, 1024, bo, out);
}